// Round 19
// baseline (191.929 us; speedup 1.0000x reference)
//
#include <hip/hip_runtime.h>

// ConvCapsMatrix EM routing, MI355X. Inputs FP32, output FP32.
// R19: W-sharing split. Block = (pos-PAIR, n-half): 512 thr = 2 pos x (32o x 8ng),
// j=18. Threads t and t+256 (same o,ng, different pos) read the IDENTICAL W row
// each j -> second position's W loads hit L1 (16 KB/j slice). W bytes through
// the per-CU L1 path halve — the R10-R18 evidence says that path (L1-thrashed
// W delivery, ~2048 cyc/CU/j vs VALU ~2832) is what pins VALUBusy at ~40%.
// State recompute is per-thread from global partials (no LDS state, no barriers).
// Launches: S0 -> S1 -> S2 -> F; partials double-buffered in d_ws by parity.

#define EPSV 1e-8f

template <int CTRL>
__device__ __forceinline__ float dppf(float v) {
  return __int_as_float(__builtin_amdgcn_update_dpp(
      0, __float_as_int(v), CTRL, 0xf, 0xf, true));
}
__device__ __forceinline__ float swz16(float v) {   // lane ^ 16 within 32-groups
  return __int_as_float(__builtin_amdgcn_ds_swizzle(__float_as_int(v), 0x401F));
}
__device__ __forceinline__ float red_max32(float v) {
  v = fmaxf(v, dppf<0xB1>(v));
  v = fmaxf(v, dppf<0x4E>(v));
  v = fmaxf(v, dppf<0x141>(v));
  v = fmaxf(v, dppf<0x140>(v));
  v = fmaxf(v, swz16(v));
  return v;
}
__device__ __forceinline__ float red_sum32(float v) {
  v += dppf<0xB1>(v);
  v += dppf<0x4E>(v);
  v += dppf<0x141>(v);
  v += dppf<0x140>(v);
  v += swz16(v);
  return v;
}

__device__ __forceinline__ void compute_votes(const float* __restrict__ Wt,
                                              const float* __restrict__ xr,
                                              int n, int o, float* __restrict__ V)
{
  // W[k,l,c,o,y,z] flat = (n*32+o)*16 + y*4+z ; xr = local pose row (16 f)
  float Wf[16];
  {
    const float* wp = Wt + (((n << 5) + o) << 4);
#pragma unroll
    for (int i = 0; i < 4; ++i) {
      const float4 q = *(const float4*)(wp + (i << 2));
      Wf[i*4+0]=q.x; Wf[i*4+1]=q.y; Wf[i*4+2]=q.z; Wf[i*4+3]=q.w;
    }
  }
  float xv[16];
#pragma unroll
  for (int i = 0; i < 4; ++i) {
    const float4 q = *(const float4*)(xr + (i << 2));
    xv[i*4+0]=q.x; xv[i*4+1]=q.y; xv[i*4+2]=q.z; xv[i*4+3]=q.w;
  }
#pragma unroll
  for (int xi = 0; xi < 4; ++xi)
#pragma unroll
    for (int z = 0; z < 4; ++z)
      V[xi*4+z] = fmaf(xv[xi*4+0], Wf[z],
                  fmaf(xv[xi*4+1], Wf[4+z],
                  fmaf(xv[xi*4+2], Wf[8+z],
                       xv[xi*4+3]* Wf[12+z])));
}

// partial segment per (pos, half): [0..511] S1 at o*16+p, [512..1023] S2,
// [1024..1055] rs(o). offset = (pos*2+half)*1056.
__global__ __launch_bounds__(512, 4) void caps_stats(
    const float* __restrict__ X, const float* __restrict__ A, const float* __restrict__ Wt,
    const float* __restrict__ Bu, const float* __restrict__ Ba,
    const float* __restrict__ prev, float* __restrict__ cur, int it)
{
  __shared__ float xp_s[2*144*16];  // both positions' half-patch poses  18432 B
  __shared__ float a_s[2*144];      // activations                        1152 B
  __shared__ float part[8*544];     // per-wave partials, 2-phase        17408 B
  __shared__ float prs[8*32];       // per-wave sum Ra                    1024 B
                                    // total ~38 KB -> 4 blocks/CU

  const int t    = threadIdx.x;
  const int o    = t & 31;
  const int ng   = (t >> 5) & 7;    // 0..7
  const int ph   = t >> 8;          // 0/1: position within the pair
  const int wv   = t >> 6;          // 0..7 (waves 0-3 = ph0, 4-7 = ph1)
  const int lane = t & 63;

  const int bid   = blockIdx.x;     // 0..575
  const int pair  = bid >> 1;
  const int half  = bid & 1;
  const int nbase = half * 144;
  const int mypos = pair*2 + ph;

  // ---- stage both positions' half-patches (144 rows each)
  for (int i = t; i < 1152; i += 512) {       // float4 chunks
    const int pp  = (i >= 576) ? 1 : 0;
    const int loc = i - pp*576;
    const int r   = loc >> 2, q4 = loc & 3;
    const int pos = pair*2 + pp;
    const int b = pos/144, r_ = pos - b*144, h = r_/12, w = r_ - (r_/12)*12;
    const int n = nbase + r;
    const int kl = n >> 5, c = n & 31;
    const int hy = h + kl/3, wx = w + (kl - (kl/3)*3);
    const float4 v = *(const float4*)(X + ((((b*14+hy)*14+wx) << 9) + (c << 4) + (q4 << 2)));
    *(float4*)(xp_s + pp*2304 + (r << 4) + (q4 << 2)) = v;
  }
  if (t < 288) {
    const int pp  = (t >= 144) ? 1 : 0;
    const int r   = t - pp*144;
    const int pos = pair*2 + pp;
    const int b = pos/144, r_ = pos - b*144, h = r_/12, w = r_ - (r_/12)*12;
    const int n = nbase + r;
    const int kl = n >> 5, c = n & 31;
    const int hy = h + kl/3, wx = w + (kl - (kl/3)*3);
    a_s[pp*144 + r] = A[((b*14+hy)*14+wx)*32 + c];
  }

  // ---- per-thread routing state, recomputed from prev partials (no LDS/barriers)
  float mu_r[16], isig_r[16];
  float la_r = 0.f, slog_r = 0.f;
  if (it > 0) {
    const float* b0 = prev + (mypos*2 + 0)*1056;
    const float* b1 = prev + (mypos*2 + 1)*1056;
    float s1[16], s2[16];
#pragma unroll
    for (int k = 0; k < 4; ++k) {
      const float4 u0 = *(const float4*)(b0 + (o << 4) + (k << 2));
      const float4 u1 = *(const float4*)(b1 + (o << 4) + (k << 2));
      s1[k*4+0]=u0.x+u1.x; s1[k*4+1]=u0.y+u1.y; s1[k*4+2]=u0.z+u1.z; s1[k*4+3]=u0.w+u1.w;
      const float4 v0 = *(const float4*)(b0 + 512 + (o << 4) + (k << 2));
      const float4 v1 = *(const float4*)(b1 + 512 + (o << 4) + (k << 2));
      s2[k*4+0]=v0.x+v1.x; s2[k*4+1]=v0.y+v1.y; s2[k*4+2]=v0.z+v1.z; s2[k*4+3]=v0.w+v1.w;
    }
    const float rsum = b0[1024+o] + b1[1024+o] + EPSV;
    float slog = 0.f;
#pragma unroll
    for (int p = 0; p < 16; ++p) {
      const float mu = s1[p] / rsum;
      float var = s2[p] / rsum - mu*mu;
      var = fmaxf(var, 0.f);
      const float sg = var + EPSV;
      mu_r[p]   = mu;
      isig_r[p] = 1.0f / sg;
      slog     += __logf(sg);
    }
    const float cost = rsum * (16.0f*Bu[o] + 0.5f*slog);
    const float av = 1.0f / (1.0f + __expf(-(Ba[o] - cost)));   // LAM=1
    la_r   = __logf(av + EPSV);
    slog_r = slog;
  } else {
#pragma unroll
    for (int p = 0; p < 16; ++p) { mu_r[p] = 0.f; isig_r[p] = 0.f; }
  }
  __syncthreads();   // staging visible

  // ---- fused stats pass over this half's 144 n's (j=18, ng stride 8)
  float S1[16], S2[16];
#pragma unroll
  for (int p = 0; p < 16; ++p) { S1[p] = 0.f; S2[p] = 0.f; }
  float rs = 0.f;

#pragma unroll 1
  for (int j = 0; j < 18; ++j) {
    const int nl = ng + (j << 3);           // local row 0..143
    const int n  = nbase + nl;              // global n: SAME for ph=0/1 -> L1 hit
    float V[16];
    compute_votes(Wt, xp_s + ph*2304 + (nl << 4), n, o, V);

    float ra;
    if (it == 0) {
      ra = a_s[ph*144 + nl] * (1.0f/32.0f);
    } else {
      float q0 = 0.f, q1 = 0.f, q2 = 0.f, q3 = 0.f;
#pragma unroll
      for (int p = 0; p < 4; ++p) {
        float d;
        d = V[p]    - mu_r[p];    q0 = fmaf(d*d, isig_r[p],    q0);
        d = V[p+4]  - mu_r[p+4];  q1 = fmaf(d*d, isig_r[p+4],  q1);
        d = V[p+8]  - mu_r[p+8];  q2 = fmaf(d*d, isig_r[p+8],  q2);
        d = V[p+12] - mu_r[p+12]; q3 = fmaf(d*d, isig_r[p+12], q3);
      }
      const float q = slog_r + ((q0 + q1) + (q2 + q3));
      const float z = la_r - 0.5f*q;
      const float m  = red_max32(z);
      const float ev = __expf(z - m);
      const float s  = red_sum32(ev);
      ra = (ev / s) * a_s[ph*144 + nl];
    }
    rs += ra;
#pragma unroll
    for (int p = 0; p < 16; ++p) {
      const float rv = ra * V[p];
      S1[p] += rv;
      S2[p] = fmaf(rv, V[p], S2[p]);
    }
  }

  // ---- pair-combine the wave's two ng's via lane^32
#pragma unroll
  for (int p = 0; p < 16; ++p) {
    S1[p] += __shfl_xor(S1[p], 32);
    S2[p] += __shfl_xor(S2[p], 32);
  }
  rs += __shfl_xor(rs, 32);

  float* seg0 = cur + ((pair*2 + 0)*2 + half)*1056;
  float* seg1 = cur + ((pair*2 + 1)*2 + half)*1056;

  // ---- phase A: S1 partials -> global (+rs)
  if (lane < 32) {
    float* p1 = part + wv*544 + o*17;
#pragma unroll
    for (int p = 0; p < 16; ++p) p1[p] = S1[p];
    prs[wv*32 + o] = rs;
  }
  __syncthreads();
  for (int c = t; c < 1024; c += 512) {
    const int pc = c >> 9, idx = c & 511;
    const int pi = idx >> 5, oo = idx & 31;
    float s = 0.f;
#pragma unroll
    for (int g = 0; g < 4; ++g) s += part[(pc*4 + g)*544 + oo*17 + pi];
    (pc ? seg1 : seg0)[(oo << 4) + pi] = s;
  }
  if (t < 64) {
    const int pc = t >> 5, oo = t & 31;
    float r = 0.f;
#pragma unroll
    for (int g = 0; g < 4; ++g) r += prs[(pc*4 + g)*32 + oo];
    (pc ? seg1 : seg0)[1024 + oo] = r;
  }
  __syncthreads();

  // ---- phase B: S2 partials -> global
  if (lane < 32) {
    float* p2 = part + wv*544 + o*17;
#pragma unroll
    for (int p = 0; p < 16; ++p) p2[p] = S2[p];
  }
  __syncthreads();
  for (int c = t; c < 1024; c += 512) {
    const int pc = c >> 9, idx = c & 511;
    const int pi = idx >> 5, oo = idx & 31;
    float s = 0.f;
#pragma unroll
    for (int g = 0; g < 4; ++g) s += part[(pc*4 + g)*544 + oo*17 + pi];
    (pc ? seg1 : seg0)[512 + (oo << 4) + pi] = s;
  }
}

// ---- final: mu/aout from last partials -> Out. One block per position.
__global__ __launch_bounds__(512, 4) void caps_final(
    const float* __restrict__ prev, const float* __restrict__ Bu,
    const float* __restrict__ Ba, float* __restrict__ Out)
{
  __shared__ float lsig_t[512];   // log sig2 at o*16+p
  __shared__ float rs_s[32], aout_s[32];

  const int t   = threadIdx.x;
  const int pos = blockIdx.x;
  const float* h0 = prev + (pos*2 + 0)*1056;
  const float* h1 = prev + (pos*2 + 1)*1056;

  const int oo = t >> 4;          // cell = (oo, pi) at flat index t = oo*16+pi
  const float rsum = h0[1024+oo] + h1[1024+oo] + EPSV;
  const float s1 = h0[t]     + h1[t];
  const float s2 = h0[512+t] + h1[512+t];
  const float mu = s1 / rsum;
  float var = s2 / rsum - mu*mu;
  var = fmaxf(var, 0.f);
  lsig_t[t] = __logf(var + EPSV);
  if ((t & 15) == 0) rs_s[oo] = rsum;
  __syncthreads();
  if (t < 32) {
    float slog = 0.f;
#pragma unroll
    for (int p = 0; p < 16; ++p) slog += lsig_t[(t << 4) + p];
    const float cost = rs_s[t] * (16.0f*Bu[t] + 0.5f*slog);
    aout_s[t] = 1.0f / (1.0f + __expf(-(Ba[t] - cost)));
  }
  __syncthreads();
  Out[pos*512 + t] = mu;          // pose flat index = o*16 + p = t (coalesced)
  if (t < 32) Out[294912 + pos*32 + t] = aout_s[t];
}

extern "C" void kernel_launch(void* const* d_in, const int* in_sizes, int n_in,
                              void* d_out, int out_size, void* d_ws, size_t ws_size,
                              hipStream_t stream) {
  (void)in_sizes; (void)n_in; (void)ws_size; (void)out_size;
  const float* X  = (const float*)d_in[0];
  const float* A  = (const float*)d_in[1];
  const float* Wt = (const float*)d_in[2];
  const float* Bu = (const float*)d_in[3];
  const float* Ba = (const float*)d_in[4];
  float* Out = (float*)d_out;

  float* pa = (float*)d_ws;                 // parity A: 1152*1056 floats
  float* pb = pa + 1152*1056;               // parity B (total ~9.7 MB)

  hipLaunchKernelGGL(caps_stats, dim3(576), dim3(512), 0, stream,
                     X, A, Wt, Bu, Ba, (const float*)nullptr, pa, 0);
  hipLaunchKernelGGL(caps_stats, dim3(576), dim3(512), 0, stream,
                     X, A, Wt, Bu, Ba, pa, pb, 1);
  hipLaunchKernelGGL(caps_stats, dim3(576), dim3(512), 0, stream,
                     X, A, Wt, Bu, Ba, pb, pa, 2);
  hipLaunchKernelGGL(caps_final, dim3(576), dim3(512), 0, stream,
                     pa, Bu, Ba, Out);
}